// Round 1
// baseline (367.004 us; speedup 1.0000x reference)
//
#include <hip/hip_runtime.h>

#define GLOBAL_AS __attribute__((address_space(1)))
#define LDS_AS    __attribute__((address_space(3)))

typedef __bf16 bf16x8 __attribute__((ext_vector_type(8)));
typedef float  f32x4  __attribute__((ext_vector_type(4)));

// Problem dims (fixed by the reference)
constexpr int SRC_STRIDE = 8192 * 80;         // floats per batch row: 655360
constexpr int TOUT       = 2728;              // output time steps
constexpr long OUT_ELEMS = (long)TOUT * 16 * 1024;  // 44695552
constexpr int SRC_ELEMS  = 32 * SRC_STRIDE;   // 20971520
constexpr int W_ELEMS    = 1024 * 640;        // 655360
constexpr int MBLK       = 341;               // 87296 / 256 (exact)
constexpr int NT         = 20;                // 640 / 32 K-tiles
constexpr int SLOT       = 16384;             // bf16 elems per LDS slot (A 8192 + B 8192)

__device__ __forceinline__ unsigned short f2bf(float f) {
    union { float f; unsigned u; } a; a.f = f;
    unsigned r = a.u + 0x7FFF + ((a.u >> 16) & 1);   // round-to-nearest-even
    return (unsigned short)(r >> 16);
}

// fp32 -> bf16 conversion, 4 elements/thread
__global__ void cvt_kernel(const float* __restrict__ in, unsigned short* __restrict__ out, int n4) {
    int i = blockIdx.x * blockDim.x + threadIdx.x;
    if (i >= n4) return;
    float4 v = ((const float4*)in)[i];
    ushort4 o;
    o.x = f2bf(v.x); o.y = f2bf(v.y); o.z = f2bf(v.z); o.w = f2bf(v.w);
    ((ushort4*)out)[i] = o;
}

// out_lengths = src_lengths // 3 - 2, written as fp32 after the main output
__global__ void lengths_kernel(const int* __restrict__ len, float* __restrict__ out) {
    int i = threadIdx.x;
    if (i < 32) out[OUT_ELEMS + i] = (float)(len[i] / 3 - 2);
}

// Fused GEMM (M=87296, N=1024, K=640) + bias + GLU epilogue.
// 256x256 tile, BK=32, 8 waves (2M x 4N), 512 threads, 128 KiB LDS as FOUR
// rotating 32-KiB slots (tile t lives in slot t%4). Deep pipeline: tiles
// t+1..t+3 are in flight while computing tile t; their DMA targets slots
// (t+1..t+3)%4 which are never the slot being read -> race-free by slot
// disjointness, no timing assumptions. Counted s_waitcnt vmcnt(8) at tile
// boundaries (never 0 in steady state); raw s_barrier (no vmcnt(0) drain);
// s_setprio(1) around each 16-MFMA cluster.
// LDS layout per slot: A = 128 lines x 64 bf16 (line = 2 rows of K=32),
// chunk-XOR swizzle: physical 16B-chunk p holds logical chunk c = p ^ (line&7)
// -> conflict-free ds_read_b128 (verified 0 conflicts in previous kernel).
// A[m][k] = srcb[(m%32)*655360 + (m/32)*240 + k]  (bf16, frame-overlapped rows)
// B[n][k] = wb[n*640 + k]                          (bf16, N x K row-major)
__global__ __launch_bounds__(512, 2)
void glu_gemm(const __bf16* __restrict__ A,
              const __bf16* __restrict__ Wb,
              const float* __restrict__ bias,
              float* __restrict__ out) {
    __shared__ __bf16 lds[4 * SLOT];   // 128 KiB

    const int tid  = threadIdx.x;
    const int lane = tid & 63;
    const int w    = tid >> 6;        // wave 0..7
    const int wm   = w >> 2;          // 0..1 (M half)
    const int wn   = w & 3;           // 0..3 (N quarter)

    // XCD-aware swizzle: all 4 bn-siblings of one bm share bid%8 -> same XCD L2.
    const int bid = blockIdx.x;
    const int bn  = (bid >> 3) & 3;
    const int bm  = (bid >> 5) * 8 + (bid & 7);
    if (bm >= MBLK) return;           // 12 idle tail blocks (343 padded to 344)

    // ---- staging lane constants ----
    // per issue: wave w writes 8 lines (16 rows), lane -> line (lane>>3), phys chunk (lane&7)
    const int sl  = lane >> 3;
    const int sp  = lane & 7;
    const int sc  = sp ^ sl;          // logical c' = (row-parity)*4 + chunk
    const int scc = (sc & 3) * 8;     // k element offset within 32-wide tile
    const int srp = sc >> 2;          // row parity
    int aG[2], bG[2];
#pragma unroll
    for (int h = 0; h < 2; ++h) {
        int R = 2 * (h * 64 + w * 8 + sl) + srp;   // row within 256-row tile
        int m = bm * 256 + R;
        aG[h] = (m & 31) * SRC_STRIDE + (m >> 5) * 240 + scc;
        int n = bn * 256 + R;
        bG[h] = n * 640 + scc;
    }
    const int aD0 = (w * 8) * 64;          // LDS dest bases (elements, wave-uniform)
    const int aD1 = (64 + w * 8) * 64;
    const int bD0 = 8192 + aD0;
    const int bD1 = 8192 + aD1;

    // ---- fragment read constants ----
    // A-frag mf: row R' = wm*128 + mf*16 + (lane&15), k-chunk = lane>>4
    // line = R'>>1; c' = (R'&1)*4 + (lane>>4); phys = c' ^ (line&7); (line&7) == ll
    const int ll  = (lane & 15) >> 1;
    const int pfr = (((lane & 1) << 2) | (lane >> 4)) ^ ll;
    const int aB  = (wm * 64 + ll) * 64 + pfr * 8;          // + mf*512 (+slot)
    const int bB  = 8192 + (wn * 32 + ll) * 64 + pfr * 8;   // + nf*512 (+slot)

    f32x4 acc[8][4] = {};

    // ---- prologue: stage tiles 0,1,2 into slots 0,1,2 (12 loads in flight) ----
#pragma unroll
    for (int t = 0; t < 3; ++t) {
        const int so = t * SLOT;
        const int kg = t * 32;
        __builtin_amdgcn_global_load_lds((const GLOBAL_AS void*)(A + (aG[0] + kg)),
                                         (LDS_AS void*)(lds + so + aD0), 16, 0, 0);
        __builtin_amdgcn_global_load_lds((const GLOBAL_AS void*)(A + (aG[1] + kg)),
                                         (LDS_AS void*)(lds + so + aD1), 16, 0, 0);
        __builtin_amdgcn_global_load_lds((const GLOBAL_AS void*)(Wb + (bG[0] + kg)),
                                         (LDS_AS void*)(lds + so + bD0), 16, 0, 0);
        __builtin_amdgcn_global_load_lds((const GLOBAL_AS void*)(Wb + (bG[1] + kg)),
                                         (LDS_AS void*)(lds + so + bD1), 16, 0, 0);
    }
    asm volatile("s_waitcnt vmcnt(8)" ::: "memory");   // tile 0 landed; 1,2 in flight
    __builtin_amdgcn_s_barrier();

    // ---- main loop: 20 tiles x 2 phases (16 MFMA + 2 stage-issues each) ----
    for (int t = 0; t < NT; ++t) {
        const int cur = (t & 3) * SLOT;
        const int nxt = ((t + 3) & 3) * SLOT;
        const int kg  = (t + 3) * 32;
        const bool st = (t < NT - 3);

        // phase A: read A mf0-3 + all B, stage next-tile A halves, MFMA lower M half
        bf16x8 af[4], bfv[4];
#pragma unroll
        for (int i = 0; i < 4; ++i)
            af[i] = *(const bf16x8*)(lds + cur + aB + i * 512);
#pragma unroll
        for (int i = 0; i < 4; ++i)
            bfv[i] = *(const bf16x8*)(lds + cur + bB + i * 512);
        if (st) {
            __builtin_amdgcn_global_load_lds((const GLOBAL_AS void*)(A + (aG[0] + kg)),
                                             (LDS_AS void*)(lds + nxt + aD0), 16, 0, 0);
            __builtin_amdgcn_global_load_lds((const GLOBAL_AS void*)(A + (aG[1] + kg)),
                                             (LDS_AS void*)(lds + nxt + aD1), 16, 0, 0);
        }
        __builtin_amdgcn_s_barrier();
        __builtin_amdgcn_s_setprio(1);
#pragma unroll
        for (int mt = 0; mt < 4; ++mt)
#pragma unroll
            for (int nt = 0; nt < 4; ++nt)
                acc[mt][nt] = __builtin_amdgcn_mfma_f32_16x16x32_bf16(
                    af[mt], bfv[nt], acc[mt][nt], 0, 0, 0);
        __builtin_amdgcn_s_setprio(0);
        __builtin_amdgcn_s_barrier();

        // phase B: read A mf4-7, stage next-tile B halves, MFMA upper M half
        bf16x8 ag[4];
#pragma unroll
        for (int i = 0; i < 4; ++i)
            ag[i] = *(const bf16x8*)(lds + cur + aB + (i + 4) * 512);
        if (st) {
            __builtin_amdgcn_global_load_lds((const GLOBAL_AS void*)(Wb + (bG[0] + kg)),
                                             (LDS_AS void*)(lds + nxt + bD0), 16, 0, 0);
            __builtin_amdgcn_global_load_lds((const GLOBAL_AS void*)(Wb + (bG[1] + kg)),
                                             (LDS_AS void*)(lds + nxt + bD1), 16, 0, 0);
        }
        __builtin_amdgcn_s_barrier();
        __builtin_amdgcn_s_setprio(1);
#pragma unroll
        for (int mt = 0; mt < 4; ++mt)
#pragma unroll
            for (int nt = 0; nt < 4; ++nt)
                acc[mt + 4][nt] = __builtin_amdgcn_mfma_f32_16x16x32_bf16(
                    ag[mt], bfv[nt], acc[mt + 4][nt], 0, 0, 0);
        __builtin_amdgcn_s_setprio(0);

        // tile boundary: wait until tile t+1 fully landed; keep 2 tiles in flight.
        // issued so far (per wave): 12 + 4*(t+1) [t<=16]; needed: 4*(t+2) -> vmcnt(8)
        if (t < NT - 3)       asm volatile("s_waitcnt vmcnt(8)" ::: "memory");
        else if (t == NT - 3) asm volatile("s_waitcnt vmcnt(4)" ::: "memory");
        else if (t == NT - 2) asm volatile("s_waitcnt vmcnt(0)" ::: "memory");
        __builtin_amdgcn_s_barrier();
    }

    // ---- epilogue: bias + GLU (value frag 2i pairs with gate frag 2i+1; same lane/reg) ----
    const int col = lane & 15;
    const int q   = lane >> 4;
    float bvs[4];
#pragma unroll
    for (int nf = 0; nf < 4; ++nf)
        bvs[nf] = bias[bn * 256 + wn * 64 + nf * 16 + col];

    const int tb = bm * 8 + wm * 4;
#pragma unroll
    for (int i = 0; i < 4; ++i) {
        const int t = tb + i;
#pragma unroll
        for (int nf = 0; nf < 4; ++nf) {
            const int n = bn * 256 + wn * 64 + nf * 16 + col;
#pragma unroll
            for (int r2 = 0; r2 < 4; ++r2) {
                const int brow = q * 4 + r2;           // b in 0..15 (value rows)
                float v = acc[2 * i][nf][r2] + bvs[nf];
                float g = acc[2 * i + 1][nf][r2] + bvs[nf];
                float s = 1.0f / (1.0f + __expf(-g));
                out[((long)(t * 16 + brow)) * 1024 + n] = v * s;
            }
        }
    }
}

extern "C" void kernel_launch(void* const* d_in, const int* in_sizes, int n_in,
                              void* d_out, int out_size, void* d_ws, size_t ws_size,
                              hipStream_t stream) {
    const float* src  = (const float*)d_in[0];
    const int*   lens = (const int*)d_in[1];
    const float* Wf   = (const float*)d_in[2];
    const float* bias = (const float*)d_in[3];
    float* out = (float*)d_out;

    unsigned short* srcb = (unsigned short*)d_ws;          // 20971520 bf16 = 41.9 MB
    unsigned short* wb   = srcb + SRC_ELEMS;               // 655360 bf16 = 1.3 MB

    // bf16 pre-pass (src + W)
    cvt_kernel<<<SRC_ELEMS / 4 / 256, 256, 0, stream>>>(src, srcb, SRC_ELEMS / 4);
    cvt_kernel<<<W_ELEMS / 4 / 256, 256, 0, stream>>>(Wf, wb, W_ELEMS / 4);

    // out_lengths
    lengths_kernel<<<1, 64, 0, stream>>>(lens, out);

    // fused GEMM + GLU: 43 groups x (4 bn x 8 bm_local) = 1376 blocks (12 idle tail)
    glu_gemm<<<43 * 32, 512, 0, stream>>>((const __bf16*)srcb, (const __bf16*)wb, bias, out);
}

// Round 2
// 362.173 us; speedup vs baseline: 1.0133x; 1.0133x over previous
//
#include <hip/hip_runtime.h>

#define GLOBAL_AS __attribute__((address_space(1)))
#define LDS_AS    __attribute__((address_space(3)))

typedef __bf16 bf16x8 __attribute__((ext_vector_type(8)));
typedef float  f32x4  __attribute__((ext_vector_type(4)));

// Problem dims (fixed by the reference)
constexpr int SRC_STRIDE = 8192 * 80;         // floats per batch row: 655360
constexpr int TOUT       = 2728;              // output time steps
constexpr long OUT_ELEMS = (long)TOUT * 16 * 1024;  // 44695552
constexpr int SRC_ELEMS  = 32 * SRC_STRIDE;   // 20971520
constexpr int W_ELEMS    = 1024 * 640;        // 655360
constexpr int MBLK       = 341;               // 87296 / 256 (exact)
constexpr int NT         = 20;                // 640 / 32 K-tiles
constexpr int SLOT       = 16384;             // bf16 elems per LDS slot (A 8192 + B 8192)

__device__ __forceinline__ unsigned short f2bf(float f) {
    union { float f; unsigned u; } a; a.f = f;
    unsigned r = a.u + 0x7FFF + ((a.u >> 16) & 1);   // round-to-nearest-even
    return (unsigned short)(r >> 16);
}

// fp32 -> bf16 conversion, 4 elements/thread
__global__ void cvt_kernel(const float* __restrict__ in, unsigned short* __restrict__ out, int n4) {
    int i = blockIdx.x * blockDim.x + threadIdx.x;
    if (i >= n4) return;
    float4 v = ((const float4*)in)[i];
    ushort4 o;
    o.x = f2bf(v.x); o.y = f2bf(v.y); o.z = f2bf(v.z); o.w = f2bf(v.w);
    ((ushort4*)out)[i] = o;
}

// out_lengths = src_lengths // 3 - 2, written as fp32 after the main output
__global__ void lengths_kernel(const int* __restrict__ len, float* __restrict__ out) {
    int i = threadIdx.x;
    if (i < 32) out[OUT_ELEMS + i] = (float)(len[i] / 3 - 2);
}

// MFMA cluster helper: one A-frag against all four live B-frags
#define MFMA_ROW(a_, i_)                                                         \
    acc[i_][0] = __builtin_amdgcn_mfma_f32_16x16x32_bf16(a_, bv0, acc[i_][0],0,0,0); \
    acc[i_][1] = __builtin_amdgcn_mfma_f32_16x16x32_bf16(a_, bv1, acc[i_][1],0,0,0); \
    acc[i_][2] = __builtin_amdgcn_mfma_f32_16x16x32_bf16(a_, bv2, acc[i_][2],0,0,0); \
    acc[i_][3] = __builtin_amdgcn_mfma_f32_16x16x32_bf16(a_, bv3, acc[i_][3],0,0,0);

// Fused GEMM (M=87296, N=1024, K=640) + bias + GLU epilogue.
// 256x256 tile, BK=32, 8 waves (2M x 4N), 512 threads, 128 KiB LDS as FOUR
// rotating 32-KiB slots (tile t in slot t%4; tiles t+1..t+3 in flight to the
// other three slots -> race-free by slot disjointness).
// KEY CHANGE vs previous round: fragment loads are inline-asm ds_read_b128
// (32-bit LDS addr + offset: immediates), NOT C++ loads of the __shared__
// array. This removes the compiler's conservative vmcnt ordering between
// outstanding global_load_lds DMA and the LDS reads (which serialized the
// whole pipeline last round). Wait discipline is manual per rule #18:
// s_waitcnt lgkmcnt(0) + sched_barrier(0) after each barrier before MFMAs;
// counted s_waitcnt vmcnt(8) at tile boundaries only (never 0 until drain).
// LDS layout per slot (unchanged, verified): A = 128 lines x 64 bf16
// (line = 2 rows of K=32), chunk-XOR swizzle phys = logical ^ (line&7).
__global__ __launch_bounds__(512, 2)
void glu_gemm(const __bf16* __restrict__ A,
              const __bf16* __restrict__ Wb,
              const float* __restrict__ bias,
              float* __restrict__ out) {
    __shared__ __bf16 lds[4 * SLOT];   // 128 KiB

    const int tid  = threadIdx.x;
    const int lane = tid & 63;
    const int w    = tid >> 6;        // wave 0..7
    const int wm   = w >> 2;          // 0..1 (M half)
    const int wn   = w & 3;           // 0..3 (N quarter)

    // XCD-aware swizzle: all 4 bn-siblings of one bm share bid%8 -> same XCD L2.
    const int bid = blockIdx.x;
    const int bn  = (bid >> 3) & 3;
    const int bm  = (bid >> 5) * 8 + (bid & 7);
    if (bm >= MBLK) return;           // 12 idle tail blocks (341 padded to 344)

    // ---- staging lane constants ----
    const int sl  = lane >> 3;
    const int sp  = lane & 7;
    const int sc  = sp ^ sl;          // logical c' = (row-parity)*4 + chunk
    const int scc = (sc & 3) * 8;     // k element offset within 32-wide tile
    const int srp = sc >> 2;          // row parity
    int aG[2], bG[2];
#pragma unroll
    for (int h = 0; h < 2; ++h) {
        int R = 2 * (h * 64 + w * 8 + sl) + srp;   // row within 256-row tile
        int m = bm * 256 + R;
        aG[h] = (m & 31) * SRC_STRIDE + (m >> 5) * 240 + scc;
        int n = bn * 256 + R;
        bG[h] = n * 640 + scc;
    }
    const int aD0 = (w * 8) * 64;          // LDS dest bases (elements, wave-uniform)
    const int aD1 = (64 + w * 8) * 64;
    const int bD0 = 8192 + aD0;
    const int bD1 = 8192 + aD1;

    // ---- fragment read constants (verified last round) ----
    // A-frag mf: row R' = wm*128 + mf*16 + (lane&15), k-chunk = lane>>4
    // line = R'>>1; c' = (R'&1)*4 + (lane>>4); phys = c' ^ (line&7); (line&7) == ll
    const int ll  = (lane & 15) >> 1;
    const int pfr = (((lane & 1) << 2) | (lane >> 4)) ^ ll;
    const int aB  = (wm * 64 + ll) * 64 + pfr * 8;          // elements
    const int bB  = 8192 + (wn * 32 + ll) * 64 + pfr * 8;   // elements

    // 32-bit LDS byte addresses for inline-asm ds_read (generic ptr low 32 = LDS offset)
    const unsigned LB    = (unsigned)(unsigned long long)(&lds[0]);
    const unsigned adrA0 = LB + 2u * (unsigned)aB;
    const unsigned adrB0 = LB + 2u * (unsigned)bB;

    f32x4 acc[8][4] = {};

    // ---- prologue: stage tiles 0,1,2 into slots 0,1,2 (12 loads in flight) ----
#pragma unroll
    for (int t = 0; t < 3; ++t) {
        const int so = t * SLOT;
        const int kg = t * 32;
        __builtin_amdgcn_global_load_lds((const GLOBAL_AS void*)(A + (aG[0] + kg)),
                                         (LDS_AS void*)(lds + so + aD0), 16, 0, 0);
        __builtin_amdgcn_global_load_lds((const GLOBAL_AS void*)(A + (aG[1] + kg)),
                                         (LDS_AS void*)(lds + so + aD1), 16, 0, 0);
        __builtin_amdgcn_global_load_lds((const GLOBAL_AS void*)(Wb + (bG[0] + kg)),
                                         (LDS_AS void*)(lds + so + bD0), 16, 0, 0);
        __builtin_amdgcn_global_load_lds((const GLOBAL_AS void*)(Wb + (bG[1] + kg)),
                                         (LDS_AS void*)(lds + so + bD1), 16, 0, 0);
    }
    asm volatile("s_waitcnt vmcnt(8)" ::: "memory");   // tile 0 landed; 1,2 in flight
    __builtin_amdgcn_s_barrier();

    // ---- main loop: 20 tiles x 2 phases (16 MFMA + 2 stage-issues each) ----
    for (int t = 0; t < NT; ++t) {
        const unsigned so16 = (unsigned)(t & 3) << 15;   // slot byte offset (32 KiB)
        const unsigned aAdr = adrA0 + so16;
        const unsigned bAdr = adrB0 + so16;
        const int nxt = ((t + 3) & 3) * SLOT;
        const int kg  = (t + 3) * 32;
        const bool st = (t < NT - 3);

        // phase A: asm-read A mf0-3 + all B, stage next-tile A halves, MFMA lower M half
        bf16x8 af0, af1, af2, af3, bv0, bv1, bv2, bv3;
        asm volatile("ds_read_b128 %0, %1 offset:0"    : "=v"(af0) : "v"(aAdr));
        asm volatile("ds_read_b128 %0, %1 offset:1024" : "=v"(af1) : "v"(aAdr));
        asm volatile("ds_read_b128 %0, %1 offset:2048" : "=v"(af2) : "v"(aAdr));
        asm volatile("ds_read_b128 %0, %1 offset:3072" : "=v"(af3) : "v"(aAdr));
        asm volatile("ds_read_b128 %0, %1 offset:0"    : "=v"(bv0) : "v"(bAdr));
        asm volatile("ds_read_b128 %0, %1 offset:1024" : "=v"(bv1) : "v"(bAdr));
        asm volatile("ds_read_b128 %0, %1 offset:2048" : "=v"(bv2) : "v"(bAdr));
        asm volatile("ds_read_b128 %0, %1 offset:3072" : "=v"(bv3) : "v"(bAdr));
        if (st) {
            __builtin_amdgcn_global_load_lds((const GLOBAL_AS void*)(A + (aG[0] + kg)),
                                             (LDS_AS void*)(lds + nxt + aD0), 16, 0, 0);
            __builtin_amdgcn_global_load_lds((const GLOBAL_AS void*)(A + (aG[1] + kg)),
                                             (LDS_AS void*)(lds + nxt + aD1), 16, 0, 0);
        }
        __builtin_amdgcn_s_barrier();
        asm volatile("s_waitcnt lgkmcnt(0)" ::: "memory");
        __builtin_amdgcn_sched_barrier(0);
        __builtin_amdgcn_s_setprio(1);
        MFMA_ROW(af0, 0) MFMA_ROW(af1, 1) MFMA_ROW(af2, 2) MFMA_ROW(af3, 3)
        __builtin_amdgcn_s_setprio(0);
        __builtin_amdgcn_s_barrier();

        // phase B: asm-read A mf4-7, stage next-tile B halves, MFMA upper M half
        bf16x8 ag0, ag1, ag2, ag3;
        asm volatile("ds_read_b128 %0, %1 offset:4096" : "=v"(ag0) : "v"(aAdr));
        asm volatile("ds_read_b128 %0, %1 offset:5120" : "=v"(ag1) : "v"(aAdr));
        asm volatile("ds_read_b128 %0, %1 offset:6144" : "=v"(ag2) : "v"(aAdr));
        asm volatile("ds_read_b128 %0, %1 offset:7168" : "=v"(ag3) : "v"(aAdr));
        if (st) {
            __builtin_amdgcn_global_load_lds((const GLOBAL_AS void*)(Wb + (bG[0] + kg)),
                                             (LDS_AS void*)(lds + nxt + bD0), 16, 0, 0);
            __builtin_amdgcn_global_load_lds((const GLOBAL_AS void*)(Wb + (bG[1] + kg)),
                                             (LDS_AS void*)(lds + nxt + bD1), 16, 0, 0);
        }
        __builtin_amdgcn_s_barrier();
        asm volatile("s_waitcnt lgkmcnt(0)" ::: "memory");
        __builtin_amdgcn_sched_barrier(0);
        __builtin_amdgcn_s_setprio(1);
        MFMA_ROW(ag0, 4) MFMA_ROW(ag1, 5) MFMA_ROW(ag2, 6) MFMA_ROW(ag3, 7)
        __builtin_amdgcn_s_setprio(0);

        // tile boundary: wait until tile t+1 fully landed; keep 2 tiles in flight.
        if (t < NT - 3)       asm volatile("s_waitcnt vmcnt(8)" ::: "memory");
        else if (t == NT - 3) asm volatile("s_waitcnt vmcnt(4)" ::: "memory");
        else if (t == NT - 2) asm volatile("s_waitcnt vmcnt(0)" ::: "memory");
        __builtin_amdgcn_s_barrier();
    }

    // ---- epilogue: bias + GLU (value frag 2i pairs with gate frag 2i+1; same lane/reg) ----
    const int col = lane & 15;
    const int q   = lane >> 4;
    float bvs[4];
#pragma unroll
    for (int nf = 0; nf < 4; ++nf)
        bvs[nf] = bias[bn * 256 + wn * 64 + nf * 16 + col];

    const int tb = bm * 8 + wm * 4;
#pragma unroll
    for (int i = 0; i < 4; ++i) {
        const int t = tb + i;
#pragma unroll
        for (int nf = 0; nf < 4; ++nf) {
            const int n = bn * 256 + wn * 64 + nf * 16 + col;
#pragma unroll
            for (int r2 = 0; r2 < 4; ++r2) {
                const int brow = q * 4 + r2;           // b in 0..15 (value rows)
                float v = acc[2 * i][nf][r2] + bvs[nf];
                float g = acc[2 * i + 1][nf][r2] + bvs[nf];
                float s = 1.0f / (1.0f + __expf(-g));
                out[((long)(t * 16 + brow)) * 1024 + n] = v * s;
            }
        }
    }
}

extern "C" void kernel_launch(void* const* d_in, const int* in_sizes, int n_in,
                              void* d_out, int out_size, void* d_ws, size_t ws_size,
                              hipStream_t stream) {
    const float* src  = (const float*)d_in[0];
    const int*   lens = (const int*)d_in[1];
    const float* Wf   = (const float*)d_in[2];
    const float* bias = (const float*)d_in[3];
    float* out = (float*)d_out;

    unsigned short* srcb = (unsigned short*)d_ws;          // 20971520 bf16 = 41.9 MB
    unsigned short* wb   = srcb + SRC_ELEMS;               // 655360 bf16 = 1.3 MB

    // bf16 pre-pass (src + W)
    cvt_kernel<<<SRC_ELEMS / 4 / 256, 256, 0, stream>>>(src, srcb, SRC_ELEMS / 4);
    cvt_kernel<<<W_ELEMS / 4 / 256, 256, 0, stream>>>(Wf, wb, W_ELEMS / 4);

    // out_lengths
    lengths_kernel<<<1, 64, 0, stream>>>(lens, out);

    // fused GEMM + GLU: 43 groups x (4 bn x 8 bm_local) = 1376 blocks (12 idle tail)
    glu_gemm<<<43 * 32, 512, 0, stream>>>((const __bf16*)srcb, (const __bf16*)wb, bias, out);
}